// Round 1
// baseline (336.696 us; speedup 1.0000x reference)
//
#include <hip/hip_runtime.h>
#include <math.h>

#define QR_M 512
#define QR_N 26
#define OUTC 512

// ---------------------------------------------------------------------------
// Kernel 1: Householder QR of (w + 1e-8), 512x26, single block of 512 threads
// (one row per thread, column data in registers). Reproduces LAPACK slarfg
// sign convention: beta = -sign(alpha)*||x||, tau = (beta-alpha)/beta,
// v = x/(alpha-beta). We only keep R (with LAPACK diagonal signs), then form
// Q = A * R^{-1} by per-row forward substitution (cond(A) ~ 1.6, so this is
// numerically equivalent to orgqr to ~1e-6). Writes Q^T as qt[d][o] ([26][512]).
// ---------------------------------------------------------------------------
__global__ __launch_bounds__(512) void qr_kernel(const float* __restrict__ w,
                                                 float* __restrict__ qt) {
  const int r = threadIdx.x;      // row 0..511
  const int lane = r & 63;
  const int wid = r >> 6;         // 8 waves

  __shared__ float part[QR_N][8]; // cross-wave reduction slots
  __shared__ float dotv[QR_N];
  __shared__ float s_alpha;
  __shared__ float Rl[QR_N][QR_N + 1]; // R staged for the solve (pad to dodge conflicts)

  float a[QR_N];
#pragma unroll
  for (int c = 0; c < QR_N; ++c) a[c] = w[r * QR_N + c] + 1e-8f;

#pragma unroll
  for (int j = 0; j < QR_N; ++j) {
    if (r == j) s_alpha = a[j];
    // ||A[j:,j]||^2 (includes alpha^2; LAPACK uses slapy2(alpha,xnorm) = same)
    float sq = (r >= j) ? a[j] * a[j] : 0.0f;
#pragma unroll
    for (int s = 32; s >= 1; s >>= 1) sq += __shfl_xor(sq, s);
    if (lane == 0) part[0][wid] = sq;
    __syncthreads();
    // every thread redundantly computes tau/scale (saves a barrier)
    float nrm2 = 0.0f;
#pragma unroll
    for (int t = 0; t < 8; ++t) nrm2 += part[0][t];
    const float alpha = s_alpha;
    const float norm  = sqrtf(nrm2);
    const float beta  = (alpha >= 0.0f) ? -norm : norm; // -sign(alpha)*norm, sign(0)=+
    const float tau   = (beta - alpha) / beta;
    const float scale = 1.0f / (alpha - beta);
    // form v in-place: v[j]=1 (implicit), v[r>j] = a_rj * scale
    float ve;
    if (r > j)       { a[j] *= scale; ve = a[j]; }
    else if (r == j) { ve = 1.0f; a[j] = beta; } // store R diagonal
    else             { ve = 0.0f; }
    // dots: w_c = v^T A[:,c] for trailing columns (butterfly per column)
#pragma unroll
    for (int c = j + 1; c < QR_N; ++c) {
      float p = ve * a[c];
#pragma unroll
      for (int s = 32; s >= 1; s >>= 1) p += __shfl_xor(p, s);
      if (lane == 0) part[c][wid] = p;
    }
    __syncthreads();
    if (r > j && r < QR_N) {
      float d = 0.0f;
#pragma unroll
      for (int t = 0; t < 8; ++t) d += part[r][t];
      dotv[r] = d * tau;
    }
    __syncthreads();
    // rank-1 update A[:,c] -= (tau * w_c) * v
#pragma unroll
    for (int c = j + 1; c < QR_N; ++c) a[c] -= dotv[c] * ve;
  }

  // stage R (rows 0..25 of the reduced matrix) into LDS
  if (r < QR_N) {
#pragma unroll
    for (int c = 0; c < QR_N; ++c) Rl[r][c] = a[c];
  }
  __syncthreads();

  // Q row r: solve y * R = A_orig[r,:]  (forward substitution in c)
  float y[QR_N];
#pragma unroll
  for (int c = 0; c < QR_N; ++c) y[c] = w[r * QR_N + c] + 1e-8f;
#pragma unroll
  for (int c = 0; c < QR_N; ++c) {
    float s = y[c];
#pragma unroll
    for (int k = 0; k < c; ++k) s -= y[k] * Rl[k][c];
    y[c] = s / Rl[c][c];
  }
  // write Q^T: qt[d][o] with o = r
#pragma unroll
  for (int c = 0; c < QR_N; ++c) qt[c * QR_M + r] = y[c];
}

// ---------------------------------------------------------------------------
// Kernel 2: out[b, o] = sum_d in[b,d] * qt[d][o].  Memory-bound (537 MB out).
// 256 threads: threads 0..127 -> row 2*bi (4 cols each via float4),
// threads 128..255 -> row 2*bi+1. Q columns held in registers (104 VGPR),
// input row loaded as 13x float2 (rows are 8B aligned), float4 stores.
// ---------------------------------------------------------------------------
__global__ __launch_bounds__(256) void dir_matmul(const float* __restrict__ x,
                                                  const float* __restrict__ qt,
                                                  float* __restrict__ out,
                                                  int nrow2) {
  const int g = threadIdx.x & 127;   // column group: cols 4g..4g+3
  const int rsel = threadIdx.x >> 7; // 0 or 1
  float4 q[QR_N];
#pragma unroll
  for (int d = 0; d < QR_N; ++d)
    q[d] = *reinterpret_cast<const float4*>(qt + d * OUTC + 4 * g);

  for (int bi = blockIdx.x; bi < nrow2; bi += gridDim.x) {
    const int row = 2 * bi + rsel;
    const float2* xr = reinterpret_cast<const float2*>(x) + row * (QR_N / 2);
    float4 acc = make_float4(0.f, 0.f, 0.f, 0.f);
#pragma unroll
    for (int d2 = 0; d2 < QR_N / 2; ++d2) {
      const float2 xv = xr[d2];
      const float4 q0 = q[2 * d2];
      const float4 q1 = q[2 * d2 + 1];
      acc.x = fmaf(xv.x, q0.x, acc.x);
      acc.y = fmaf(xv.x, q0.y, acc.y);
      acc.z = fmaf(xv.x, q0.z, acc.z);
      acc.w = fmaf(xv.x, q0.w, acc.w);
      acc.x = fmaf(xv.y, q1.x, acc.x);
      acc.y = fmaf(xv.y, q1.y, acc.y);
      acc.z = fmaf(xv.y, q1.z, acc.z);
      acc.w = fmaf(xv.y, q1.w, acc.w);
    }
    *reinterpret_cast<float4*>(out + (size_t)row * OUTC + 4 * g) = acc;
  }
}

extern "C" void kernel_launch(void* const* d_in, const int* in_sizes, int n_in,
                              void* d_out, int out_size, void* d_ws, size_t ws_size,
                              hipStream_t stream) {
  const float* input  = (const float*)d_in[0];   // [B, 26] f32
  const float* weight = (const float*)d_in[1];   // [512, 26] f32
  float* out = (float*)d_out;                    // [B, 512] f32
  float* qt  = (float*)d_ws;                     // [26][512] f32 scratch (53 KB)

  const int B = in_sizes[0] / QR_N;              // 262144

  qr_kernel<<<1, 512, 0, stream>>>(weight, qt);
  dir_matmul<<<2048, 256, 0, stream>>>(input, qt, out, B / 2);
}

// Round 2
// 300.768 us; speedup vs baseline: 1.1195x; 1.1195x over previous
//
#include <hip/hip_runtime.h>
#include <math.h>

#define QR_M 512
#define QR_N 26
#define OUTC 512

using half8_t = __attribute__((ext_vector_type(8))) _Float16;
using f32x4   = __attribute__((ext_vector_type(4))) float;

// ---------------------------------------------------------------------------
// Kernel 1: Householder QR of (w + 1e-8), 512x26, ONE wave (64 threads),
// 8 rows per thread (row = i*64 + t). All reductions are in-register 64-lane
// shfl_xor butterflies -> zero __syncthreads in the factorization loop.
// LAPACK slarfg sign convention: beta = -sign(alpha)*||x||. Q formed as
// A * R^{-1} (forward substitution; cond(A)~1.6 so error ~1e-6).
// Emits Q as f16, row-major [512][32] with k=26..31 zero-padded (MFMA B^T).
// ---------------------------------------------------------------------------
__global__ __launch_bounds__(64) void qr_kernel(const float* __restrict__ w,
                                                _Float16* __restrict__ qf) {
  const int t = threadIdx.x;  // 0..63; thread owns rows i*64+t, i=0..7

  float a[8][QR_N];
#pragma unroll
  for (int i = 0; i < 8; ++i) {
    const float2* wp = reinterpret_cast<const float2*>(w + (size_t)(i * 64 + t) * QR_N);
#pragma unroll
    for (int c2 = 0; c2 < QR_N / 2; ++c2) {
      float2 v = wp[c2];
      a[i][2 * c2]     = v.x + 1e-8f;
      a[i][2 * c2 + 1] = v.y + 1e-8f;
    }
  }

  __shared__ float Rl[QR_N][QR_N + 1];

#pragma unroll
  for (int j = 0; j < QR_N; ++j) {
    // alpha = current diagonal entry (row j lives at i=0, lane j)
    const float alpha = __shfl(a[0][j], j);
    // ||A[j:,j]||^2 : i=0 rows are t (mask t>=j); i>=1 rows are >=64 (always in)
    float sq = (t >= j) ? a[0][j] * a[0][j] : 0.0f;
#pragma unroll
    for (int i = 1; i < 8; ++i) sq += a[i][j] * a[i][j];
#pragma unroll
    for (int s = 32; s >= 1; s >>= 1) sq += __shfl_xor(sq, s);

    const float norm  = sqrtf(sq);
    const float beta  = (alpha >= 0.0f) ? -norm : norm;  // -sign(alpha)*norm
    const float tau   = (beta - alpha) / beta;
    const float scale = 1.0f / (alpha - beta);

    // Householder vector elements for this thread's rows; v[j]=1 implicit
    float ve[8];
    {
      const float av = a[0][j] * scale;
      ve[0] = (t > j) ? av : ((t == j) ? 1.0f : 0.0f);
      if (t > j)  a[0][j] = av;    // (kept; unused later)
      if (t == j) a[0][j] = beta;  // R diagonal
    }
#pragma unroll
    for (int i = 1; i < 8; ++i) { a[i][j] *= scale; ve[i] = a[i][j]; }

    // trailing update: A[:,c] -= tau * (v^T A[:,c]) * v
#pragma unroll
    for (int c = j + 1; c < QR_N; ++c) {
      float p = ve[0] * a[0][c];
#pragma unroll
      for (int i = 1; i < 8; ++i) p += ve[i] * a[i][c];
#pragma unroll
      for (int s = 32; s >= 1; s >>= 1) p += __shfl_xor(p, s);
      const float tw = tau * p;
#pragma unroll
      for (int i = 0; i < 8; ++i) a[i][c] -= tw * ve[i];
    }
  }

  // stage R (rows 0..25 = i=0 lanes 0..25) to LDS for the solve
  if (t < QR_N) {
#pragma unroll
    for (int c = 0; c < QR_N; ++c) Rl[t][c] = a[0][c];
  }
  __syncthreads();

  float rinv[QR_N];
#pragma unroll
  for (int c = 0; c < QR_N; ++c) rinv[c] = 1.0f / Rl[c][c];

  // Q row r: solve y * R = A_orig[r,:]; write as f16 with K padded to 32
#pragma unroll
  for (int i = 0; i < 8; ++i) {
    const int r = i * 64 + t;
    float y[QR_N];
    const float2* wp = reinterpret_cast<const float2*>(w + (size_t)r * QR_N);
#pragma unroll
    for (int c2 = 0; c2 < QR_N / 2; ++c2) {
      float2 v = wp[c2];
      y[2 * c2]     = v.x + 1e-8f;
      y[2 * c2 + 1] = v.y + 1e-8f;
    }
#pragma unroll
    for (int c = 0; c < QR_N; ++c) {
      float s = y[c];
#pragma unroll
      for (int k = 0; k < c; ++k) s -= y[k] * Rl[k][c];
      y[c] = s * rinv[c];
    }
    _Float16* qr_row = qf + (size_t)r * 32;
#pragma unroll
    for (int c = 0; c < QR_N; ++c) qr_row[c] = (_Float16)y[c];
#pragma unroll
    for (int c = QR_N; c < 32; ++c) qr_row[c] = (_Float16)0.0f;
  }
}

// ---------------------------------------------------------------------------
// Kernel 2: out[b,o] = sum_d x[b,d] * Q[o,d] via mfma_f32_16x16x32_f16.
// A = x[16 rows][K=32 padded], B^T = Q[16 cols][K=32] (both: lane l holds 8
// contiguous k at k0=(l>>4)*8 of row/col l&15). C/D: col=lane&15,
// row=(lane>>4)*4+reg (m89-verified). Each wave: 16 rows x all 512 cols
// (32 N-tiles, B-frags preloaded in 128 VGPRs). Memory-bound streaming:
// 537 MB writes + 27 MB x reads.
// ---------------------------------------------------------------------------
__global__ __launch_bounds__(256) void dir_matmul(const float* __restrict__ x,
                                                  const _Float16* __restrict__ qf,
                                                  float* __restrict__ out,
                                                  int nblk64) {
  const int tid  = threadIdx.x;
  const int wid  = tid >> 6;
  const int l    = tid & 63;
  const int rloc = l & 15;
  const int grp  = l >> 4;
  const int k0   = grp * 8;

  // preload all 32 B-fragments (Q) — reused across grid-stride iterations
  half8_t bq[32];
#pragma unroll
  for (int t2 = 0; t2 < 32; ++t2)
    bq[t2] = *reinterpret_cast<const half8_t*>(qf + (size_t)(t2 * 16 + rloc) * 32 + k0);

  for (int rb = blockIdx.x; rb < nblk64; rb += gridDim.x) {
    const int row = rb * 64 + wid * 16 + rloc;
    // A fragment: 8 f32 at k0..k0+7 of row, f16-converted; k>=26 zeroed
    float xv[8];
    const float* xp = x + (size_t)row * QR_N + k0;
    if (grp < 3) {
#pragma unroll
      for (int e = 0; e < 4; ++e) {
        float2 v = *reinterpret_cast<const float2*>(xp + 2 * e);
        xv[2 * e]     = v.x;
        xv[2 * e + 1] = v.y;
      }
    } else {
      float2 v = *reinterpret_cast<const float2*>(xp);
      xv[0] = v.x; xv[1] = v.y;
#pragma unroll
      for (int e = 2; e < 8; ++e) xv[e] = 0.0f;
    }
    half8_t av;
#pragma unroll
    for (int e = 0; e < 8; ++e) av[e] = (_Float16)xv[e];

    float* ob = out + (size_t)(rb * 64 + wid * 16 + grp * 4) * OUTC + rloc;
#pragma unroll
    for (int t2 = 0; t2 < 32; ++t2) {
      f32x4 acc = {0.0f, 0.0f, 0.0f, 0.0f};
      acc = __builtin_amdgcn_mfma_f32_16x16x32_f16(av, bq[t2], acc, 0, 0, 0);
#pragma unroll
      for (int j = 0; j < 4; ++j)
        ob[(size_t)j * OUTC + t2 * 16] = acc[j];
    }
  }
}

extern "C" void kernel_launch(void* const* d_in, const int* in_sizes, int n_in,
                              void* d_out, int out_size, void* d_ws, size_t ws_size,
                              hipStream_t stream) {
  const float* input  = (const float*)d_in[0];   // [B, 26] f32
  const float* weight = (const float*)d_in[1];   // [512, 26] f32
  float* out = (float*)d_out;                    // [B, 512] f32
  _Float16* qf = (_Float16*)d_ws;                // [512][32] f16 scratch (32 KB)

  const int B = in_sizes[0] / QR_N;              // 262144
  const int nblk64 = B / 64;                     // 4096

  qr_kernel<<<1, 64, 0, stream>>>(weight, qf);
  dir_matmul<<<2048, 256, 0, stream>>>(input, qf, out, nblk64);
}

// Round 3
// 201.879 us; speedup vs baseline: 1.6678x; 1.4898x over previous
//
#include <hip/hip_runtime.h>
#include <math.h>

#define QR_M 512
#define QR_N 26
#define OUTC 512

using half8_t = __attribute__((ext_vector_type(8))) _Float16;
using f32x4   = __attribute__((ext_vector_type(4))) float;

// ---------------------------------------------------------------------------
// Kernel 1: Householder QR of (w + 1e-8), 512x26, 512 threads (one row per
// thread, 26 VGPR working set -> no spill risk). LAPACK slarfg sign
// convention: beta = -sign(alpha)*||x||. Q = A * R^{-1} via per-row forward
// substitution (cond(A)~1.6 -> ~1e-6 error). Emits Q as f16 row-major
// [512][32], k=26..31 zero-padded (MFMA B^T fragment layout).
// This is the round-1 structure that passed with absmax 0.0039.
// ---------------------------------------------------------------------------
__global__ __launch_bounds__(512) void qr_kernel(const float* __restrict__ w,
                                                 _Float16* __restrict__ qf) {
  const int r = threadIdx.x;      // row 0..511
  const int lane = r & 63;
  const int wid = r >> 6;         // 8 waves

  __shared__ float part[QR_N][8]; // cross-wave reduction slots
  __shared__ float dotv[QR_N];
  __shared__ float s_alpha;
  __shared__ float Rl[QR_N][QR_N + 1];

  float a[QR_N];
#pragma unroll
  for (int c = 0; c < QR_N; ++c) a[c] = w[r * QR_N + c] + 1e-8f;

#pragma unroll
  for (int j = 0; j < QR_N; ++j) {
    if (r == j) s_alpha = a[j];
    float sq = (r >= j) ? a[j] * a[j] : 0.0f;
#pragma unroll
    for (int s = 32; s >= 1; s >>= 1) sq += __shfl_xor(sq, s);
    if (lane == 0) part[0][wid] = sq;
    __syncthreads();
    float nrm2 = 0.0f;
#pragma unroll
    for (int t = 0; t < 8; ++t) nrm2 += part[0][t];
    const float alpha = s_alpha;
    const float norm  = sqrtf(nrm2);
    const float beta  = (alpha >= 0.0f) ? -norm : norm; // -sign(alpha)*norm
    const float tau   = (beta - alpha) / beta;
    const float scale = 1.0f / (alpha - beta);
    float ve;
    if (r > j)       { a[j] *= scale; ve = a[j]; }
    else if (r == j) { ve = 1.0f; a[j] = beta; } // R diagonal
    else             { ve = 0.0f; }
#pragma unroll
    for (int c = j + 1; c < QR_N; ++c) {
      float p = ve * a[c];
#pragma unroll
      for (int s = 32; s >= 1; s >>= 1) p += __shfl_xor(p, s);
      if (lane == 0) part[c][wid] = p;
    }
    __syncthreads();
    if (r > j && r < QR_N) {
      float d = 0.0f;
#pragma unroll
      for (int t = 0; t < 8; ++t) d += part[r][t];
      dotv[r] = d * tau;
    }
    __syncthreads();
#pragma unroll
    for (int c = j + 1; c < QR_N; ++c) a[c] -= dotv[c] * ve;
  }

  if (r < QR_N) {
#pragma unroll
    for (int c = 0; c < QR_N; ++c) Rl[r][c] = a[c];
  }
  __syncthreads();

  // Q row r: solve y * R = A_orig[r,:] (forward substitution)
  float y[QR_N];
#pragma unroll
  for (int c = 0; c < QR_N; ++c) y[c] = w[r * QR_N + c] + 1e-8f;
#pragma unroll
  for (int c = 0; c < QR_N; ++c) {
    float s = y[c];
#pragma unroll
    for (int k = 0; k < c; ++k) s -= y[k] * Rl[k][c];
    y[c] = s / Rl[c][c];
  }
  _Float16* qrow = qf + (size_t)r * 32;
#pragma unroll
  for (int c = 0; c < QR_N; ++c) qrow[c] = (_Float16)y[c];
#pragma unroll
  for (int c = QR_N; c < 32; ++c) qrow[c] = (_Float16)0.0f;
}

// ---------------------------------------------------------------------------
// Kernel 2: out[b,o] = sum_d x[b,d] * Q[o,d] via mfma_f32_16x16x32_f16,
// with an LDS-transposed epilogue for fully-coalesced dwordx4 stores.
// Block = 256 thr / 4 waves, covers 32 rows x 512 cols per iteration:
//   wave w: rows (w>>1)*16..+15, cols (w&1)*256..+255 (16 N-tiles, bq[16]
//   = 64 VGPR so the kernel fits 4 waves/SIMD).
// Epilogue per 8-tile chunk: acc -> LDS [16][132] (pad 4: 2-way-free write
// banks, rows stay 16B-aligned for ds_read_b128) -> 32 lanes read one row
// (512 contiguous B) -> global float4 stores.
// ---------------------------------------------------------------------------
__global__ __launch_bounds__(256, 4) void dir_matmul(const float* __restrict__ x,
                                                     const _Float16* __restrict__ qf,
                                                     float* __restrict__ out,
                                                     int nblk32) {
  const int tid   = threadIdx.x;
  const int wid   = tid >> 6;
  const int l     = tid & 63;
  const int rloc  = l & 15;
  const int grp   = l >> 4;
  const int k0    = grp * 8;
  const int rhalf = (wid >> 1) * 16;   // row half: 0 or 16
  const int chalf = (wid & 1) * 256;   // col half: 0 or 256
  const int t2b   = (wid & 1) * 16;    // N-tile base

  __shared__ float tile[4][16 * 132];  // per-wave 16x128 f32, pad 4
  float* tw = tile[wid];

  // preload this wave's 16 B-fragments (Q) — reused across iterations
  half8_t bq[16];
#pragma unroll
  for (int t2 = 0; t2 < 16; ++t2)
    bq[t2] = *reinterpret_cast<const half8_t*>(
        qf + (size_t)((t2b + t2) * 16 + rloc) * 32 + k0);

  for (int rb = blockIdx.x; rb < nblk32; rb += gridDim.x) {
    const int row = rb * 32 + rhalf + rloc;
    // A fragment: x[row][k0..k0+7] as f16; k>=26 zeroed
    half8_t av;
    const float* xp = x + (size_t)row * QR_N + k0;
    if (grp < 3) {
#pragma unroll
      for (int e = 0; e < 4; ++e) {
        float2 v = *reinterpret_cast<const float2*>(xp + 2 * e);
        av[2 * e]     = (_Float16)v.x;
        av[2 * e + 1] = (_Float16)v.y;
      }
    } else {
      float2 v = *reinterpret_cast<const float2*>(xp);
      av[0] = (_Float16)v.x; av[1] = (_Float16)v.y;
#pragma unroll
      for (int e = 2; e < 8; ++e) av[e] = (_Float16)0.0f;
    }

#pragma unroll
    for (int cc = 0; cc < 2; ++cc) {
      // 8 MFMA tiles -> LDS (transposed staging)
#pragma unroll
      for (int tt = 0; tt < 8; ++tt) {
        f32x4 acc = {0.0f, 0.0f, 0.0f, 0.0f};
        acc = __builtin_amdgcn_mfma_f32_16x16x32_f16(av, bq[cc * 8 + tt], acc, 0, 0, 0);
#pragma unroll
        for (int j = 0; j < 4; ++j)
          tw[(grp * 4 + j) * 132 + tt * 16 + rloc] = acc[j];
      }
      __syncthreads();
      // coalesced read-back + global float4 stores
#pragma unroll
      for (int it = 0; it < 8; ++it) {
        const int r  = it * 2 + (l >> 5);
        const int cg = l & 31;
        f32x4 v = *reinterpret_cast<const f32x4*>(&tw[r * 132 + 4 * cg]);
        *reinterpret_cast<f32x4*>(
            out + (size_t)(rb * 32 + rhalf + r) * OUTC + chalf + cc * 128 + 4 * cg) = v;
      }
      __syncthreads();
    }
  }
}

extern "C" void kernel_launch(void* const* d_in, const int* in_sizes, int n_in,
                              void* d_out, int out_size, void* d_ws, size_t ws_size,
                              hipStream_t stream) {
  const float* input  = (const float*)d_in[0];   // [B, 26] f32
  const float* weight = (const float*)d_in[1];   // [512, 26] f32
  float* out = (float*)d_out;                    // [B, 512] f32
  _Float16* qf = (_Float16*)d_ws;                // [512][32] f16 scratch (32 KB)

  const int B = in_sizes[0] / QR_N;              // 262144
  const int nblk32 = B / 32;                     // 8192

  qr_kernel<<<1, 512, 0, stream>>>(weight, qf);
  dir_matmul<<<2048, 256, 0, stream>>>(input, qf, out, nblk32);
}